// Round 6
// baseline (514.745 us; speedup 1.0000x reference)
//
#include <hip/hip_runtime.h>

#define NN 50000
#define NE 800000

// ---- bf16 helpers (manual RNE; values are finite) --------------------------
__device__ inline unsigned short f2bf(float f) {
    unsigned u = __float_as_uint(f);
    unsigned r = (u + 0x7FFFu + ((u >> 16) & 1u)) >> 16;
    return (unsigned short)r;
}
__device__ inline float bf2f(unsigned short h) {
    return __uint_as_float(((unsigned)h) << 16);
}

// X stored as 8 COLUMN PLANES: plane p holds cols [8p, 8p+8) for all rows:
// Xh[p*NN*8 + row*8 + (col-8p)]. One plane = 50000*8*2B = 0.8MB -> fits a
// 4MiB per-XCD L2 with room to spare. Gather blocks pick their plane via
// blockIdx&7, which round-robins onto the 8 XCDs, so each XCD's working set
// is ONE plane (the 6.4MB row-major table missed/replicated across L2s).
__device__ inline void store_x_plane(unsigned short* Xh, int r, int col, ushort4 h) {
    unsigned short* plane = Xh + (size_t)(col >> 3) * ((size_t)NN * 8);
    *reinterpret_cast<ushort4*>(plane + (size_t)r * 8 + (col & 7)) = h;
}

// ---- fused: degree/cursor atomics + proj0 (feat @ W0, UNscaled) ------------
// Degree role is memory-side atomic-RMW bound (~33B/atomic of HBM traffic;
// in-flight depth doesn't matter, r3/r4). proj0 rides along on the
// otherwise-idle CUs. Role by blockIdx: bid%3==0 -> degree block (391 blocks,
// 2048 edges, 8/thread), else proj tile (782). dout_is scaling lives in
// gather-0 ((s*x)@W == s*(x@W)).
__global__ __launch_bounds__(256) void fused_build_proj0_kernel(
    const float* __restrict__ A,          // feat, lda=256
    const float* __restrict__ W,          // 256x64 row-major
    unsigned short* __restrict__ Xh,      // bf16 out, 8 planes [NN][8]
    const int* __restrict__ src, const int* __restrict__ dst,
    int* __restrict__ dout_cnt, int* __restrict__ cursor,
    int* __restrict__ epos) {
    __shared__ float sAT[64 * 68];  // [k][row], pitch 68
    __shared__ float sW[64 * 64];   // [k][col]

    const int bid = blockIdx.x;
    if (bid % 3 == 0) {
        // ---- degree / CSR-slot role: 8 edges per thread, atomics unrolled --
        const int d = bid / 3;                  // 0..390
        const int e0 = d * 2048 + threadIdx.x;  // stride-256 over 8 slots
        int s[8], dn[8], p[8];
#pragma unroll
        for (int j = 0; j < 8; ++j) {
            int e = e0 + j * 256;
            if (e < NE) { s[j] = src[e]; dn[j] = dst[e]; } else dn[j] = -1;
        }
#pragma unroll
        for (int j = 0; j < 8; ++j)
            if (dn[j] >= 0) p[j] = atomicAdd(&cursor[dn[j]], 1);
#pragma unroll
        for (int j = 0; j < 8; ++j)
            if (dn[j] >= 0) atomicAdd(&dout_cnt[s[j]], 1);
#pragma unroll
        for (int j = 0; j < 8; ++j) {
            int e = e0 + j * 256;
            if (e < NE) epos[e] = p[j];
        }
        return;
    }

    // ---- proj role: 64x64 tile of X = feat @ W0 (no scale) ----
    const int p = bid - bid / 3 - 1;          // tile id 0..781
    constexpr int lda = 256;
    constexpr int KC = 64;
    constexpr int NCHUNK = 4;                 // K = 256
    float acc[4][4] = {};

    const int t = threadIdx.x;
    const int tx = t & 15;
    const int ty = t >> 4;
    const int row0 = p * 64;

    const int srow = t & 63;
    const int f0 = t >> 6;
    int grow = row0 + srow;
    if (grow > NN - 1) grow = NN - 1;         // clamp: loads always in-bounds
    const float* arow = A + (size_t)grow * lda;

    for (int kc = 0; kc < NCHUNK; ++kc) {
#pragma unroll
        for (int it = 0; it < 4; ++it) {
            int k = (f0 + it * 4) * 4;
            float4 a4 = *reinterpret_cast<const float4*>(arow + kc * KC + k);
            sAT[(k + 0) * 68 + srow] = a4.x;
            sAT[(k + 1) * 68 + srow] = a4.y;
            sAT[(k + 2) * 68 + srow] = a4.z;
            sAT[(k + 3) * 68 + srow] = a4.w;
        }
        {
            const float4* wsrc = reinterpret_cast<const float4*>(W + (size_t)kc * KC * 64);
            float4* wdst = reinterpret_cast<float4*>(sW);
#pragma unroll
            for (int it = 0; it < 4; ++it) wdst[t + it * 256] = wsrc[t + it * 256];
        }
        __syncthreads();
#pragma unroll 8
        for (int k = 0; k < KC; ++k) {
            float4 av = *reinterpret_cast<const float4*>(&sAT[k * 68 + ty * 4]);
            float4 wv = *reinterpret_cast<const float4*>(&sW[k * 64 + tx * 4]);
            acc[0][0] = fmaf(av.x, wv.x, acc[0][0]);
            acc[0][1] = fmaf(av.x, wv.y, acc[0][1]);
            acc[0][2] = fmaf(av.x, wv.z, acc[0][2]);
            acc[0][3] = fmaf(av.x, wv.w, acc[0][3]);
            acc[1][0] = fmaf(av.y, wv.x, acc[1][0]);
            acc[1][1] = fmaf(av.y, wv.y, acc[1][1]);
            acc[1][2] = fmaf(av.y, wv.z, acc[1][2]);
            acc[1][3] = fmaf(av.y, wv.w, acc[1][3]);
            acc[2][0] = fmaf(av.z, wv.x, acc[2][0]);
            acc[2][1] = fmaf(av.z, wv.y, acc[2][1]);
            acc[2][2] = fmaf(av.z, wv.z, acc[2][2]);
            acc[2][3] = fmaf(av.z, wv.w, acc[2][3]);
            acc[3][0] = fmaf(av.w, wv.x, acc[3][0]);
            acc[3][1] = fmaf(av.w, wv.y, acc[3][1]);
            acc[3][2] = fmaf(av.w, wv.z, acc[3][2]);
            acc[3][3] = fmaf(av.w, wv.w, acc[3][3]);
        }
        __syncthreads();
    }
#pragma unroll
    for (int i = 0; i < 4; ++i) {
        int r = row0 + ty * 4 + i;
        if (r < NN) {
            ushort4 h = {f2bf(acc[i][0]), f2bf(acc[i][1]), f2bf(acc[i][2]), f2bf(acc[i][3])};
            store_x_plane(Xh, r, tx * 4, h);
        }
    }
}

// ---- scan helpers ----------------------------------------------------------
__device__ inline int wave_incl_scan(int v) {
    int lane = threadIdx.x & 63;
#pragma unroll
    for (int off = 1; off < 64; off <<= 1) {
        int t = __shfl_up(v, off, 64);
        if (lane >= off) v += t;
    }
    return v;
}

// A: per-block local exclusive scan of in-degree; block totals to partials
__global__ void scan_local_kernel(const int* __restrict__ din_cnt,
                                  int* __restrict__ row_start,
                                  int* __restrict__ partials) {
    __shared__ int wsum[4];
    int i = blockIdx.x * 256 + threadIdx.x;
    int v = (i < NN) ? din_cnt[i] : 0;
    int lane = threadIdx.x & 63, wid = threadIdx.x >> 6;
    int incl = wave_incl_scan(v);
    if (lane == 63) wsum[wid] = incl;
    __syncthreads();
    if (threadIdx.x == 0) {
        int s = 0;
        for (int w = 0; w < 4; ++w) { int t = wsum[w]; wsum[w] = s; s += t; }
        partials[blockIdx.x] = s;
    }
    __syncthreads();
    if (i < NN) row_start[i] = incl - v + wsum[wid];
}

// B: single-block exclusive scan of the 196 partials (in place)
__global__ void scan_partials_kernel(int* __restrict__ partials, int nparts,
                                     int* __restrict__ row_start) {
    __shared__ int wsum[4];
    int v = (threadIdx.x < nparts) ? partials[threadIdx.x] : 0;
    int lane = threadIdx.x & 63, wid = threadIdx.x >> 6;
    int incl = wave_incl_scan(v);
    if (lane == 63) wsum[wid] = incl;
    __syncthreads();
    if (threadIdx.x == 0) {
        int s = 0;
        for (int w = 0; w < 4; ++w) { int t = wsum[w]; wsum[w] = s; s += t; }
        row_start[NN] = NE;  // total in-degree == edge count
    }
    __syncthreads();
    if (threadIdx.x < nparts) partials[threadIdx.x] = incl - v + wsum[wid];
}

// C: add block offsets + emit rsqrt normalizers (fused, one pass over nodes)
__global__ void scan_add_norm_kernel(int* __restrict__ row_start, const int* __restrict__ partials,
                                     const int* __restrict__ dout_cnt, const int* __restrict__ din_cnt,
                                     float* __restrict__ dout_is, float* __restrict__ din_is) {
    int i = blockIdx.x * 256 + threadIdx.x;
    if (i < NN) {
        row_start[i] += partials[blockIdx.x];
        dout_is[i] = rsqrtf(fmaxf((float)dout_cnt[i], 1.0f));
        din_is[i]  = rsqrtf(fmaxf((float)din_cnt[i], 1.0f));
    }
}

// fill CSR: atomic-free scattered write using precomputed slots
__global__ void csr_fill_kernel(const int* __restrict__ src, const int* __restrict__ dst,
                                const int* __restrict__ row_start, const int* __restrict__ epos,
                                int* __restrict__ csr_src) {
    int e = blockIdx.x * 256 + threadIdx.x;
    if (e < NE) csr_src[row_start[dst[e]] + epos[e]] = src[e];
}

// ---- X = rowscale(A) @ W, register-blocked 64x64 tile (layers 1-3, tail) ---
template <int K, bool OUT_BF16>
__global__ __launch_bounds__(256) void proj_kernel(
    const float* __restrict__ A, int lda,
    const float* __restrict__ W,   // K x 64, row-major
    const float* __restrict__ scale,
    void* __restrict__ Xout) {
    constexpr int KC = 64;
    constexpr int NCHUNK = K / KC;
    __shared__ float sAT[KC * 68];  // [k][row], pitch 68
    __shared__ float sW[KC * 64];   // [k][col]
    float acc[4][4] = {};

    const int t = threadIdx.x;
    const int tx = t & 15;          // col group: cols 4*tx..4*tx+3
    const int ty = t >> 4;          // row group: rows 4*ty..4*ty+3
    const int row0 = blockIdx.x * 64;

    const int srow = t & 63;        // staging: one row per lane
    const int f0 = t >> 6;          // staging float4-col base (0..3)
    int grow = row0 + srow;
    if (grow > NN - 1) grow = NN - 1;   // clamp: loads always in-bounds
    const float* arow = A + (size_t)grow * lda;

    for (int kc = 0; kc < NCHUNK; ++kc) {
#pragma unroll
        for (int it = 0; it < 4; ++it) {
            int k = (f0 + it * 4) * 4;
            float4 a4 = *reinterpret_cast<const float4*>(arow + kc * KC + k);
            sAT[(k + 0) * 68 + srow] = a4.x;
            sAT[(k + 1) * 68 + srow] = a4.y;
            sAT[(k + 2) * 68 + srow] = a4.z;
            sAT[(k + 3) * 68 + srow] = a4.w;
        }
        {
            const float4* wsrc = reinterpret_cast<const float4*>(W + (size_t)kc * KC * 64);
            float4* wdst = reinterpret_cast<float4*>(sW);
#pragma unroll
            for (int it = 0; it < 4; ++it) wdst[t + it * 256] = wsrc[t + it * 256];
        }
        __syncthreads();
#pragma unroll 8
        for (int k = 0; k < KC; ++k) {
            float4 av = *reinterpret_cast<const float4*>(&sAT[k * 68 + ty * 4]);
            float4 wv = *reinterpret_cast<const float4*>(&sW[k * 64 + tx * 4]);
            acc[0][0] = fmaf(av.x, wv.x, acc[0][0]);
            acc[0][1] = fmaf(av.x, wv.y, acc[0][1]);
            acc[0][2] = fmaf(av.x, wv.z, acc[0][2]);
            acc[0][3] = fmaf(av.x, wv.w, acc[0][3]);
            acc[1][0] = fmaf(av.y, wv.x, acc[1][0]);
            acc[1][1] = fmaf(av.y, wv.y, acc[1][1]);
            acc[1][2] = fmaf(av.y, wv.z, acc[1][2]);
            acc[1][3] = fmaf(av.y, wv.w, acc[1][3]);
            acc[2][0] = fmaf(av.z, wv.x, acc[2][0]);
            acc[2][1] = fmaf(av.z, wv.y, acc[2][1]);
            acc[2][2] = fmaf(av.z, wv.z, acc[2][2]);
            acc[2][3] = fmaf(av.z, wv.w, acc[2][3]);
            acc[3][0] = fmaf(av.w, wv.x, acc[3][0]);
            acc[3][1] = fmaf(av.w, wv.y, acc[3][1]);
            acc[3][2] = fmaf(av.w, wv.z, acc[3][2]);
            acc[3][3] = fmaf(av.w, wv.w, acc[3][3]);
        }
        __syncthreads();
    }
#pragma unroll
    for (int i = 0; i < 4; ++i) {
        int r = row0 + ty * 4 + i;
        if (r < NN) {
            float s = scale ? scale[r] : 1.0f;
            float4 o = {acc[i][0] * s, acc[i][1] * s, acc[i][2] * s, acc[i][3] * s};
            if (OUT_BF16) {
                ushort4 h = {f2bf(o.x), f2bf(o.y), f2bf(o.z), f2bf(o.w)};
                store_x_plane((unsigned short*)Xout, r, tx * 4, h);
            } else {
                *reinterpret_cast<float4*>((float*)Xout + (size_t)r * 64 + tx * 4) = o;
            }
        }
    }
}

// ---- pull aggregation, XCD-plane-partitioned ------------------------------
// Block bid handles column plane cg=bid&7 for 16 dst rows (rowblk=bid>>3).
// Consecutive bids round-robin across the 8 XCDs, so all blocks on an XCD
// read the SAME 0.8MB plane -> per-XCD L2 resident (the r5 temporal split
// failed because both halves ran concurrently; this split is spatial).
// Wave = 4 groups x 16 lanes; each lane loads one neighbor's full 16B plane
// slice (uint4) -> 64 independent loads in flight per wave. In-group
// 4-round shuffle reduce; lane 0 stores 8 f32 cols.
// SSCALE: multiply each neighbor row by sscale[src] (layer 0: dout_is moved
// here from proj0; 200KB table, L2-resident).
template <bool SSCALE>
__device__ inline void acc8(float* a, uint4 v, float w) {
    unsigned d0 = v.x, d1 = v.y, d2 = v.z, d3 = v.w;
    if (SSCALE) {
        a[0] = fmaf(__uint_as_float(d0 << 16), w, a[0]);
        a[1] = fmaf(__uint_as_float(d0 & 0xFFFF0000u), w, a[1]);
        a[2] = fmaf(__uint_as_float(d1 << 16), w, a[2]);
        a[3] = fmaf(__uint_as_float(d1 & 0xFFFF0000u), w, a[3]);
        a[4] = fmaf(__uint_as_float(d2 << 16), w, a[4]);
        a[5] = fmaf(__uint_as_float(d2 & 0xFFFF0000u), w, a[5]);
        a[6] = fmaf(__uint_as_float(d3 << 16), w, a[6]);
        a[7] = fmaf(__uint_as_float(d3 & 0xFFFF0000u), w, a[7]);
    } else {
        a[0] += __uint_as_float(d0 << 16);
        a[1] += __uint_as_float(d0 & 0xFFFF0000u);
        a[2] += __uint_as_float(d1 << 16);
        a[3] += __uint_as_float(d1 & 0xFFFF0000u);
        a[4] += __uint_as_float(d2 << 16);
        a[5] += __uint_as_float(d2 & 0xFFFF0000u);
        a[6] += __uint_as_float(d3 << 16);
        a[7] += __uint_as_float(d3 & 0xFFFF0000u);
    }
}

template <bool SSCALE>
__global__ __launch_bounds__(256) void gather_xcd_kernel(
    const int* __restrict__ row_start, const int* __restrict__ csr_src,
    const unsigned short* __restrict__ Xh,   // 8 planes [NN][8]
    const float* __restrict__ din_is, const float* __restrict__ sscale,
    const float* __restrict__ b, float* __restrict__ out,
    int ldo, int coff, int relu) {
    const int bid = blockIdx.x;
    const int cg = bid & 7;                  // column plane == XCD (heuristic)
    const int rowblk = bid >> 3;             // 0..3124
    const int t = threadIdx.x;
    const int grp = t >> 4;                  // row group 0..15
    const int j = t & 15;                    // lane within group
    const int n = rowblk * 16 + grp;         // dst row (3125*16 == NN exactly)
    const unsigned short* Xp = Xh + (size_t)cg * ((size_t)NN * 8);
    const int s0 = row_start[n], s1 = row_start[n + 1];
    float a[8] = {};
    for (int i = s0 + j; i < s1; i += 16) {
        int id = csr_src[i];
        uint4 v = *reinterpret_cast<const uint4*>(Xp + (size_t)id * 8);
        float w = SSCALE ? sscale[id] : 1.0f;
        acc8<SSCALE>(a, v, w);
    }
    // reduce over the 16 lanes of the group (xor offsets < 16 stay in-group)
#pragma unroll
    for (int off = 1; off < 16; off <<= 1) {
#pragma unroll
        for (int k = 0; k < 8; ++k) a[k] += __shfl_xor(a[k], off, 64);
    }
    if (j == 0) {
        const int cb = cg * 8;               // column within the 64-wide output
        float4 o0, o1;
        if (relu) {
            float di = din_is[n];
            o0.x = fmaxf(fmaf(a[0], di, b[cb + 0]), 0.0f);
            o0.y = fmaxf(fmaf(a[1], di, b[cb + 1]), 0.0f);
            o0.z = fmaxf(fmaf(a[2], di, b[cb + 2]), 0.0f);
            o0.w = fmaxf(fmaf(a[3], di, b[cb + 3]), 0.0f);
            o1.x = fmaxf(fmaf(a[4], di, b[cb + 4]), 0.0f);
            o1.y = fmaxf(fmaf(a[5], di, b[cb + 5]), 0.0f);
            o1.z = fmaxf(fmaf(a[6], di, b[cb + 6]), 0.0f);
            o1.w = fmaxf(fmaf(a[7], di, b[cb + 7]), 0.0f);
        } else {
            o0.x = a[0] + b[cb + 0];
            o0.y = a[1] + b[cb + 1];
            o0.z = a[2] + b[cb + 2];
            o0.w = a[3] + b[cb + 3];
            o1.x = a[4] + b[cb + 4];
            o1.y = a[5] + b[cb + 5];
            o1.z = a[6] + b[cb + 6];
            o1.w = a[7] + b[cb + 7];
        }
        float* op = out + (size_t)n * ldo + coff + cb;
        *reinterpret_cast<float4*>(op) = o0;
        *reinterpret_cast<float4*>(op + 4) = o1;
    }
}

extern "C" void kernel_launch(void* const* d_in, const int* in_sizes, int n_in,
                              void* d_out, int out_size, void* d_ws, size_t ws_size,
                              hipStream_t stream) {
    const float* feat  = (const float*)d_in[0];
    const int*   src   = (const int*)d_in[1];
    const int*   dst   = (const int*)d_in[2];
    const float* W[4]  = {(const float*)d_in[3], (const float*)d_in[5],
                          (const float*)d_in[7], (const float*)d_in[9]};
    const float* b[4]  = {(const float*)d_in[4], (const float*)d_in[6],
                          (const float*)d_in[8], (const float*)d_in[10]};
    const float* W_mlp = (const float*)d_in[11];
    const float* b_mlp = (const float*)d_in[12];
    float* out = (float*)d_out;

    // workspace layout:
    // C [NN*256 f]  (head transiently reused: dout_cnt [NN i] | cursor [NN i]
    //               | epos [NE i] — all dead before gather-0 writes C)
    // X [NN*64 f]   (bf16 8-plane view aliases the same region)
    // dout_is [NN f] | din_is [NN f] |
    // row_start [NN+1 i] | partials [256 i] | csr_src [NE i]
    float* C        = (float*)d_ws;
    int*   dout_cnt = (int*)d_ws;            // NN
    int*   cursor   = dout_cnt + NN;         // NN (doubles as din_cnt)
    int*   epos     = cursor + NN;           // NE
    float* X        = C + (size_t)NN * 256;
    unsigned short* Xh = (unsigned short*)X; // bf16 planes (used disjointly in time)
    float* dout_is  = X + (size_t)NN * 64;
    float* din_is   = dout_is + NN;
    int*   row_start = (int*)(din_is + NN);
    int*   partials  = row_start + NN + 1;
    int*   csr_src   = partials + 256;

    const int NBLK = (NN + 255) / 256;   // 196
    const int GBLK = (NN + 63) / 64;     // 782 (GEMM tiles)
    const int EBLK = (NE + 255) / 256;   // 3125
    const int DEGBLK = (NE + 2047) / 2048;  // 391 degree blocks (8 edges/thread)
    const int FBLK = GBLK + DEGBLK;      // 1173 fused blocks (391 degree @ bid%3==0)
    const int GATBLK = 8 * ((NN + 15) / 16); // 25000 gather blocks (plane = bid&7)

    // zero dout_cnt + cursor (contiguous)
    hipMemsetAsync(dout_cnt, 0, 2 * NN * sizeof(int), stream);

    // fused: degree/cursor atomic pass overlapped with proj0 (unscaled feat@W0)
    fused_build_proj0_kernel<<<FBLK, 256, 0, stream>>>(feat, W[0], Xh,
                                                       src, dst, dout_cnt, cursor, epos);

    // row_start = exscan(cursor); fill is atomic-free
    scan_local_kernel<<<NBLK, 256, 0, stream>>>(cursor, row_start, partials);
    scan_partials_kernel<<<1, 256, 0, stream>>>(partials, NBLK, row_start);
    scan_add_norm_kernel<<<NBLK, 256, 0, stream>>>(row_start, partials, dout_cnt, cursor,
                                                   dout_is, din_is);
    csr_fill_kernel<<<EBLK, 256, 0, stream>>>(src, dst, row_start, epos, csr_src);

    // layer 0: X holds UNscaled feat@W0; dout_is applied per-src-row in gather
    gather_xcd_kernel<true><<<GATBLK, 256, 0, stream>>>(row_start, csr_src, Xh, din_is,
                                                        dout_is, b[0], C, 256, 0, 1);

    // layers 1..3 (K = 64), input = previous slice of C — bf16 X, pre-scaled
    for (int i = 1; i < 4; ++i) {
        proj_kernel<64, true><<<GBLK, 256, 0, stream>>>(C + (i - 1) * 64, 256, W[i], dout_is, Xh);
        gather_xcd_kernel<false><<<GATBLK, 256, 0, stream>>>(row_start, csr_src, Xh, din_is,
                                                             nullptr, b[i], C, 256, i * 64, 1);
    }

    // tail: P = C @ W_mlp as bf16 (project BEFORE the neighbor-sum; linear),
    // then out = b_mlp + segment_sum(P[src] -> dst)
    proj_kernel<256, true><<<GBLK, 256, 0, stream>>>(C, 256, W_mlp, nullptr, Xh);
    gather_xcd_kernel<false><<<GATBLK, 256, 0, stream>>>(row_start, csr_src, Xh, nullptr,
                                                         nullptr, b_mlp, out, 64, 0, 0);
}

// Round 7
// 475.936 us; speedup vs baseline: 1.0815x; 1.0815x over previous
//
#include <hip/hip_runtime.h>

#define NN 50000
#define NE 800000

// ---- bf16 helpers (manual RNE; values are finite) --------------------------
__device__ inline unsigned short f2bf(float f) {
    unsigned u = __float_as_uint(f);
    unsigned r = (u + 0x7FFFu + ((u >> 16) & 1u)) >> 16;
    return (unsigned short)r;
}
__device__ inline float bf2f(unsigned short h) {
    return __uint_as_float(((unsigned)h) << 16);
}

// X stored as TWO column planes: plane p holds cols [32p, 32p+32):
// Xh[p*NN*32 + row*32 + (col-32p)]. One plane = 50000*32*2B = 3.2MB, which
// fits a 4MiB per-XCD L2. Each gather layer runs as TWO SEQUENTIAL dispatches
// (half=0 then half=1) so the live table slice at any instant is one plane.
// (r5 failed: both halves in ONE dispatch ran concurrently, footprint never
// shrank. r6 failed: 8-way block split re-read the index list 8x and used
// 16B of each 64B line. Here: 64B/row/plane = full line, index read 1x/pass.)
__device__ inline void store_x_plane(unsigned short* Xh, int r, int col, ushort4 h) {
    unsigned short* plane = Xh + (size_t)(col >> 5) * ((size_t)NN * 32);
    *reinterpret_cast<ushort4*>(plane + (size_t)r * 32 + (col & 31)) = h;
}

// ---- fused: degree/cursor atomics + proj0 (feat @ W0, UNscaled) ------------
// Degree role is memory-side atomic-RMW bound (~33B/atomic of HBM traffic;
// in-flight depth doesn't matter, r3/r4). proj0 rides along on the
// otherwise-idle CUs. Role by blockIdx: bid%3==0 -> degree block (391 blocks,
// 2048 edges, 8/thread), else proj tile (782). dout_is scaling lives in
// gather-0 ((s*x)@W == s*(x@W)).
__global__ __launch_bounds__(256) void fused_build_proj0_kernel(
    const float* __restrict__ A,          // feat, lda=256
    const float* __restrict__ W,          // 256x64 row-major
    unsigned short* __restrict__ Xh,      // bf16 out, 2 planes [NN][32]
    const int* __restrict__ src, const int* __restrict__ dst,
    int* __restrict__ dout_cnt, int* __restrict__ cursor,
    int* __restrict__ epos) {
    __shared__ float sAT[64 * 68];  // [k][row], pitch 68
    __shared__ float sW[64 * 64];   // [k][col]

    const int bid = blockIdx.x;
    if (bid % 3 == 0) {
        // ---- degree / CSR-slot role: 8 edges per thread, atomics unrolled --
        const int d = bid / 3;                  // 0..390
        const int e0 = d * 2048 + threadIdx.x;  // stride-256 over 8 slots
        int s[8], dn[8], p[8];
#pragma unroll
        for (int j = 0; j < 8; ++j) {
            int e = e0 + j * 256;
            if (e < NE) { s[j] = src[e]; dn[j] = dst[e]; } else dn[j] = -1;
        }
#pragma unroll
        for (int j = 0; j < 8; ++j)
            if (dn[j] >= 0) p[j] = atomicAdd(&cursor[dn[j]], 1);
#pragma unroll
        for (int j = 0; j < 8; ++j)
            if (dn[j] >= 0) atomicAdd(&dout_cnt[s[j]], 1);
#pragma unroll
        for (int j = 0; j < 8; ++j) {
            int e = e0 + j * 256;
            if (e < NE) epos[e] = p[j];
        }
        return;
    }

    // ---- proj role: 64x64 tile of X = feat @ W0 (no scale) ----
    const int p = bid - bid / 3 - 1;          // tile id 0..781
    constexpr int lda = 256;
    constexpr int KC = 64;
    constexpr int NCHUNK = 4;                 // K = 256
    float acc[4][4] = {};

    const int t = threadIdx.x;
    const int tx = t & 15;
    const int ty = t >> 4;
    const int row0 = p * 64;

    const int srow = t & 63;
    const int f0 = t >> 6;
    int grow = row0 + srow;
    if (grow > NN - 1) grow = NN - 1;         // clamp: loads always in-bounds
    const float* arow = A + (size_t)grow * lda;

    for (int kc = 0; kc < NCHUNK; ++kc) {
#pragma unroll
        for (int it = 0; it < 4; ++it) {
            int k = (f0 + it * 4) * 4;
            float4 a4 = *reinterpret_cast<const float4*>(arow + kc * KC + k);
            sAT[(k + 0) * 68 + srow] = a4.x;
            sAT[(k + 1) * 68 + srow] = a4.y;
            sAT[(k + 2) * 68 + srow] = a4.z;
            sAT[(k + 3) * 68 + srow] = a4.w;
        }
        {
            const float4* wsrc = reinterpret_cast<const float4*>(W + (size_t)kc * KC * 64);
            float4* wdst = reinterpret_cast<float4*>(sW);
#pragma unroll
            for (int it = 0; it < 4; ++it) wdst[t + it * 256] = wsrc[t + it * 256];
        }
        __syncthreads();
#pragma unroll 8
        for (int k = 0; k < KC; ++k) {
            float4 av = *reinterpret_cast<const float4*>(&sAT[k * 68 + ty * 4]);
            float4 wv = *reinterpret_cast<const float4*>(&sW[k * 64 + tx * 4]);
            acc[0][0] = fmaf(av.x, wv.x, acc[0][0]);
            acc[0][1] = fmaf(av.x, wv.y, acc[0][1]);
            acc[0][2] = fmaf(av.x, wv.z, acc[0][2]);
            acc[0][3] = fmaf(av.x, wv.w, acc[0][3]);
            acc[1][0] = fmaf(av.y, wv.x, acc[1][0]);
            acc[1][1] = fmaf(av.y, wv.y, acc[1][1]);
            acc[1][2] = fmaf(av.y, wv.z, acc[1][2]);
            acc[1][3] = fmaf(av.y, wv.w, acc[1][3]);
            acc[2][0] = fmaf(av.z, wv.x, acc[2][0]);
            acc[2][1] = fmaf(av.z, wv.y, acc[2][1]);
            acc[2][2] = fmaf(av.z, wv.z, acc[2][2]);
            acc[2][3] = fmaf(av.z, wv.w, acc[2][3]);
            acc[3][0] = fmaf(av.w, wv.x, acc[3][0]);
            acc[3][1] = fmaf(av.w, wv.y, acc[3][1]);
            acc[3][2] = fmaf(av.w, wv.z, acc[3][2]);
            acc[3][3] = fmaf(av.w, wv.w, acc[3][3]);
        }
        __syncthreads();
    }
#pragma unroll
    for (int i = 0; i < 4; ++i) {
        int r = row0 + ty * 4 + i;
        if (r < NN) {
            ushort4 h = {f2bf(acc[i][0]), f2bf(acc[i][1]), f2bf(acc[i][2]), f2bf(acc[i][3])};
            store_x_plane(Xh, r, tx * 4, h);
        }
    }
}

// ---- scan helpers ----------------------------------------------------------
__device__ inline int wave_incl_scan(int v) {
    int lane = threadIdx.x & 63;
#pragma unroll
    for (int off = 1; off < 64; off <<= 1) {
        int t = __shfl_up(v, off, 64);
        if (lane >= off) v += t;
    }
    return v;
}

// A: per-block local exclusive scan of in-degree; block totals to partials
__global__ void scan_local_kernel(const int* __restrict__ din_cnt,
                                  int* __restrict__ row_start,
                                  int* __restrict__ partials) {
    __shared__ int wsum[4];
    int i = blockIdx.x * 256 + threadIdx.x;
    int v = (i < NN) ? din_cnt[i] : 0;
    int lane = threadIdx.x & 63, wid = threadIdx.x >> 6;
    int incl = wave_incl_scan(v);
    if (lane == 63) wsum[wid] = incl;
    __syncthreads();
    if (threadIdx.x == 0) {
        int s = 0;
        for (int w = 0; w < 4; ++w) { int t = wsum[w]; wsum[w] = s; s += t; }
        partials[blockIdx.x] = s;
    }
    __syncthreads();
    if (i < NN) row_start[i] = incl - v + wsum[wid];
}

// B: single-block exclusive scan of the 196 partials (in place)
__global__ void scan_partials_kernel(int* __restrict__ partials, int nparts,
                                     int* __restrict__ row_start) {
    __shared__ int wsum[4];
    int v = (threadIdx.x < nparts) ? partials[threadIdx.x] : 0;
    int lane = threadIdx.x & 63, wid = threadIdx.x >> 6;
    int incl = wave_incl_scan(v);
    if (lane == 63) wsum[wid] = incl;
    __syncthreads();
    if (threadIdx.x == 0) {
        int s = 0;
        for (int w = 0; w < 4; ++w) { int t = wsum[w]; wsum[w] = s; s += t; }
        row_start[NN] = NE;  // total in-degree == edge count
    }
    __syncthreads();
    if (threadIdx.x < nparts) partials[threadIdx.x] = incl - v + wsum[wid];
}

// C: add block offsets + emit rsqrt normalizers (fused, one pass over nodes)
__global__ void scan_add_norm_kernel(int* __restrict__ row_start, const int* __restrict__ partials,
                                     const int* __restrict__ dout_cnt, const int* __restrict__ din_cnt,
                                     float* __restrict__ dout_is, float* __restrict__ din_is) {
    int i = blockIdx.x * 256 + threadIdx.x;
    if (i < NN) {
        row_start[i] += partials[blockIdx.x];
        dout_is[i] = rsqrtf(fmaxf((float)dout_cnt[i], 1.0f));
        din_is[i]  = rsqrtf(fmaxf((float)din_cnt[i], 1.0f));
    }
}

// fill CSR: atomic-free scattered write using precomputed slots
__global__ void csr_fill_kernel(const int* __restrict__ src, const int* __restrict__ dst,
                                const int* __restrict__ row_start, const int* __restrict__ epos,
                                int* __restrict__ csr_src) {
    int e = blockIdx.x * 256 + threadIdx.x;
    if (e < NE) csr_src[row_start[dst[e]] + epos[e]] = src[e];
}

// ---- X = rowscale(A) @ W, register-blocked 64x64 tile (layers 1-3, tail) ---
template <int K, bool OUT_BF16>
__global__ __launch_bounds__(256) void proj_kernel(
    const float* __restrict__ A, int lda,
    const float* __restrict__ W,   // K x 64, row-major
    const float* __restrict__ scale,
    void* __restrict__ Xout) {
    constexpr int KC = 64;
    constexpr int NCHUNK = K / KC;
    __shared__ float sAT[KC * 68];  // [k][row], pitch 68
    __shared__ float sW[KC * 64];   // [k][col]
    float acc[4][4] = {};

    const int t = threadIdx.x;
    const int tx = t & 15;          // col group: cols 4*tx..4*tx+3
    const int ty = t >> 4;          // row group: rows 4*ty..4*ty+3
    const int row0 = blockIdx.x * 64;

    const int srow = t & 63;        // staging: one row per lane
    const int f0 = t >> 6;          // staging float4-col base (0..3)
    int grow = row0 + srow;
    if (grow > NN - 1) grow = NN - 1;   // clamp: loads always in-bounds
    const float* arow = A + (size_t)grow * lda;

    for (int kc = 0; kc < NCHUNK; ++kc) {
#pragma unroll
        for (int it = 0; it < 4; ++it) {
            int k = (f0 + it * 4) * 4;
            float4 a4 = *reinterpret_cast<const float4*>(arow + kc * KC + k);
            sAT[(k + 0) * 68 + srow] = a4.x;
            sAT[(k + 1) * 68 + srow] = a4.y;
            sAT[(k + 2) * 68 + srow] = a4.z;
            sAT[(k + 3) * 68 + srow] = a4.w;
        }
        {
            const float4* wsrc = reinterpret_cast<const float4*>(W + (size_t)kc * KC * 64);
            float4* wdst = reinterpret_cast<float4*>(sW);
#pragma unroll
            for (int it = 0; it < 4; ++it) wdst[t + it * 256] = wsrc[t + it * 256];
        }
        __syncthreads();
#pragma unroll 8
        for (int k = 0; k < KC; ++k) {
            float4 av = *reinterpret_cast<const float4*>(&sAT[k * 68 + ty * 4]);
            float4 wv = *reinterpret_cast<const float4*>(&sW[k * 64 + tx * 4]);
            acc[0][0] = fmaf(av.x, wv.x, acc[0][0]);
            acc[0][1] = fmaf(av.x, wv.y, acc[0][1]);
            acc[0][2] = fmaf(av.x, wv.z, acc[0][2]);
            acc[0][3] = fmaf(av.x, wv.w, acc[0][3]);
            acc[1][0] = fmaf(av.y, wv.x, acc[1][0]);
            acc[1][1] = fmaf(av.y, wv.y, acc[1][1]);
            acc[1][2] = fmaf(av.y, wv.z, acc[1][2]);
            acc[1][3] = fmaf(av.y, wv.w, acc[1][3]);
            acc[2][0] = fmaf(av.z, wv.x, acc[2][0]);
            acc[2][1] = fmaf(av.z, wv.y, acc[2][1]);
            acc[2][2] = fmaf(av.z, wv.z, acc[2][2]);
            acc[2][3] = fmaf(av.z, wv.w, acc[2][3]);
            acc[3][0] = fmaf(av.w, wv.x, acc[3][0]);
            acc[3][1] = fmaf(av.w, wv.y, acc[3][1]);
            acc[3][2] = fmaf(av.w, wv.z, acc[3][2]);
            acc[3][3] = fmaf(av.w, wv.w, acc[3][3]);
        }
        __syncthreads();
    }
#pragma unroll
    for (int i = 0; i < 4; ++i) {
        int r = row0 + ty * 4 + i;
        if (r < NN) {
            float s = scale ? scale[r] : 1.0f;
            float4 o = {acc[i][0] * s, acc[i][1] * s, acc[i][2] * s, acc[i][3] * s};
            if (OUT_BF16) {
                ushort4 h = {f2bf(o.x), f2bf(o.y), f2bf(o.z), f2bf(o.w)};
                store_x_plane((unsigned short*)Xout, r, tx * 4, h);
            } else {
                *reinterpret_cast<float4*>((float*)Xout + (size_t)r * 64 + tx * 4) = o;
            }
        }
    }
}

// ---- pull aggregation: one column-half per SEQUENTIAL dispatch -------------
// 12500 blocks, 4 rows/block, one wave per dst row. Wave = 16 neighbor
// groups x 4 lanes; group g covers neighbor i=s0+g (+16/iter); each lane
// loads one 16B quarter of the neighbor's 64B plane slice (full line used).
// 2-deep unroll -> 32 lines in flight/wave. 4-round xor reduce across
// groups; group-0 lanes store 8 f32 cols each (32 cols = the half).
// SSCALE: multiply each neighbor row by sscale[src] (layer 0: dout_is moved
// here from proj0; 200KB table, L2-resident).
template <bool SSCALE>
__device__ inline void acc8(float* a, uint4 v, float w) {
    unsigned d0 = v.x, d1 = v.y, d2 = v.z, d3 = v.w;
    if (SSCALE) {
        a[0] = fmaf(__uint_as_float(d0 << 16), w, a[0]);
        a[1] = fmaf(__uint_as_float(d0 & 0xFFFF0000u), w, a[1]);
        a[2] = fmaf(__uint_as_float(d1 << 16), w, a[2]);
        a[3] = fmaf(__uint_as_float(d1 & 0xFFFF0000u), w, a[3]);
        a[4] = fmaf(__uint_as_float(d2 << 16), w, a[4]);
        a[5] = fmaf(__uint_as_float(d2 & 0xFFFF0000u), w, a[5]);
        a[6] = fmaf(__uint_as_float(d3 << 16), w, a[6]);
        a[7] = fmaf(__uint_as_float(d3 & 0xFFFF0000u), w, a[7]);
    } else {
        a[0] += __uint_as_float(d0 << 16);
        a[1] += __uint_as_float(d0 & 0xFFFF0000u);
        a[2] += __uint_as_float(d1 << 16);
        a[3] += __uint_as_float(d1 & 0xFFFF0000u);
        a[4] += __uint_as_float(d2 << 16);
        a[5] += __uint_as_float(d2 & 0xFFFF0000u);
        a[6] += __uint_as_float(d3 << 16);
        a[7] += __uint_as_float(d3 & 0xFFFF0000u);
    }
}

template <bool SSCALE>
__global__ __launch_bounds__(256) void gather_half_kernel(
    const int* __restrict__ row_start, const int* __restrict__ csr_src,
    const unsigned short* __restrict__ Xh,   // 2 planes [NN][32]
    const float* __restrict__ din_is, const float* __restrict__ sscale,
    const float* __restrict__ b, float* __restrict__ out,
    int ldo, int coff, int relu, int half) {
    const int n = blockIdx.x * 4 + (threadIdx.x >> 6);   // 12500*4 == NN
    const int lane = threadIdx.x & 63;
    const int g = lane >> 2;        // neighbor group 0..15
    const int j = lane & 3;         // quad lane: cols j*8..j*8+7 of the half
    const unsigned short* Xp = Xh + (size_t)half * ((size_t)NN * 32);
    const int s0 = row_start[n], s1 = row_start[n + 1];
    float a[8] = {};
    int i = s0 + g;
    // 2-deep: both i and i+16 in range
    for (; i + 16 < s1; i += 32) {
        int ia = csr_src[i];
        int ib = csr_src[i + 16];
        uint4 va = *reinterpret_cast<const uint4*>(Xp + (size_t)ia * 32 + j * 8);
        uint4 vb = *reinterpret_cast<const uint4*>(Xp + (size_t)ib * 32 + j * 8);
        float wa = SSCALE ? sscale[ia] : 1.0f;
        float wb = SSCALE ? sscale[ib] : 1.0f;
        acc8<SSCALE>(a, va, wa);
        acc8<SSCALE>(a, vb, wb);
    }
    if (i < s1) {
        int ia = csr_src[i];
        uint4 va = *reinterpret_cast<const uint4*>(Xp + (size_t)ia * 32 + j * 8);
        float wa = SSCALE ? sscale[ia] : 1.0f;
        acc8<SSCALE>(a, va, wa);
    }
    // reduce across the 16 groups (lanes sharing lane&3 hold the same cols)
#pragma unroll
    for (int off = 4; off < 64; off <<= 1) {
#pragma unroll
        for (int k = 0; k < 8; ++k) a[k] += __shfl_xor(a[k], off, 64);
    }
    if (g == 0) {
        const int cb = half * 32 + j * 8;  // column within the 64-wide output
        float4 o0, o1;
        if (relu) {
            float di = din_is[n];
            o0.x = fmaxf(fmaf(a[0], di, b[cb + 0]), 0.0f);
            o0.y = fmaxf(fmaf(a[1], di, b[cb + 1]), 0.0f);
            o0.z = fmaxf(fmaf(a[2], di, b[cb + 2]), 0.0f);
            o0.w = fmaxf(fmaf(a[3], di, b[cb + 3]), 0.0f);
            o1.x = fmaxf(fmaf(a[4], di, b[cb + 4]), 0.0f);
            o1.y = fmaxf(fmaf(a[5], di, b[cb + 5]), 0.0f);
            o1.z = fmaxf(fmaf(a[6], di, b[cb + 6]), 0.0f);
            o1.w = fmaxf(fmaf(a[7], di, b[cb + 7]), 0.0f);
        } else {
            o0.x = a[0] + b[cb + 0];
            o0.y = a[1] + b[cb + 1];
            o0.z = a[2] + b[cb + 2];
            o0.w = a[3] + b[cb + 3];
            o1.x = a[4] + b[cb + 4];
            o1.y = a[5] + b[cb + 5];
            o1.z = a[6] + b[cb + 6];
            o1.w = a[7] + b[cb + 7];
        }
        float* op = out + (size_t)n * ldo + coff + cb;
        *reinterpret_cast<float4*>(op) = o0;
        *reinterpret_cast<float4*>(op + 4) = o1;
    }
}

extern "C" void kernel_launch(void* const* d_in, const int* in_sizes, int n_in,
                              void* d_out, int out_size, void* d_ws, size_t ws_size,
                              hipStream_t stream) {
    const float* feat  = (const float*)d_in[0];
    const int*   src   = (const int*)d_in[1];
    const int*   dst   = (const int*)d_in[2];
    const float* W[4]  = {(const float*)d_in[3], (const float*)d_in[5],
                          (const float*)d_in[7], (const float*)d_in[9]};
    const float* b[4]  = {(const float*)d_in[4], (const float*)d_in[6],
                          (const float*)d_in[8], (const float*)d_in[10]};
    const float* W_mlp = (const float*)d_in[11];
    const float* b_mlp = (const float*)d_in[12];
    float* out = (float*)d_out;

    // workspace layout:
    // C [NN*256 f]  (head transiently reused: dout_cnt [NN i] | cursor [NN i]
    //               | epos [NE i] — all dead before gather-0 writes C)
    // X [NN*64 f]   (bf16 2-plane view aliases the same region)
    // dout_is [NN f] | din_is [NN f] |
    // row_start [NN+1 i] | partials [256 i] | csr_src [NE i]
    float* C        = (float*)d_ws;
    int*   dout_cnt = (int*)d_ws;            // NN
    int*   cursor   = dout_cnt + NN;         // NN (doubles as din_cnt)
    int*   epos     = cursor + NN;           // NE
    float* X        = C + (size_t)NN * 256;
    unsigned short* Xh = (unsigned short*)X; // bf16 planes (used disjointly in time)
    float* dout_is  = X + (size_t)NN * 64;
    float* din_is   = dout_is + NN;
    int*   row_start = (int*)(din_is + NN);
    int*   partials  = row_start + NN + 1;
    int*   csr_src   = partials + 256;

    const int NBLK = (NN + 255) / 256;   // 196
    const int GBLK = (NN + 63) / 64;     // 782 (GEMM tiles)
    const int EBLK = (NE + 255) / 256;   // 3125
    const int DEGBLK = (NE + 2047) / 2048;  // 391 degree blocks (8 edges/thread)
    const int FBLK = GBLK + DEGBLK;      // 1173 fused blocks (391 degree @ bid%3==0)
    const int HGBLK = NN / 4;            // 12500 gather blocks per half-pass

    // zero dout_cnt + cursor (contiguous)
    hipMemsetAsync(dout_cnt, 0, 2 * NN * sizeof(int), stream);

    // fused: degree/cursor atomic pass overlapped with proj0 (unscaled feat@W0)
    fused_build_proj0_kernel<<<FBLK, 256, 0, stream>>>(feat, W[0], Xh,
                                                       src, dst, dout_cnt, cursor, epos);

    // row_start = exscan(cursor); fill is atomic-free
    scan_local_kernel<<<NBLK, 256, 0, stream>>>(cursor, row_start, partials);
    scan_partials_kernel<<<1, 256, 0, stream>>>(partials, NBLK, row_start);
    scan_add_norm_kernel<<<NBLK, 256, 0, stream>>>(row_start, partials, dout_cnt, cursor,
                                                   dout_is, din_is);
    csr_fill_kernel<<<EBLK, 256, 0, stream>>>(src, dst, row_start, epos, csr_src);

    // layer 0: X holds UNscaled feat@W0; dout_is applied per-src-row in gather
    for (int h = 0; h < 2; ++h)
        gather_half_kernel<true><<<HGBLK, 256, 0, stream>>>(row_start, csr_src, Xh, din_is,
                                                            dout_is, b[0], C, 256, 0, 1, h);

    // layers 1..3 (K = 64), input = previous slice of C — bf16 X, pre-scaled
    for (int i = 1; i < 4; ++i) {
        proj_kernel<64, true><<<GBLK, 256, 0, stream>>>(C + (i - 1) * 64, 256, W[i], dout_is, Xh);
        for (int h = 0; h < 2; ++h)
            gather_half_kernel<false><<<HGBLK, 256, 0, stream>>>(row_start, csr_src, Xh, din_is,
                                                                 nullptr, b[i], C, 256, i * 64, 1, h);
    }

    // tail: P = C @ W_mlp as bf16 (project BEFORE the neighbor-sum; linear),
    // then out = b_mlp + segment_sum(P[src] -> dst)
    proj_kernel<256, true><<<GBLK, 256, 0, stream>>>(C, 256, W_mlp, nullptr, Xh);
    for (int h = 0; h < 2; ++h)
        gather_half_kernel<false><<<HGBLK, 256, 0, stream>>>(row_start, csr_src, Xh, nullptr,
                                                             nullptr, b_mlp, out, 64, 0, 0, h);
}

// Round 9
// 409.913 us; speedup vs baseline: 1.2557x; 1.1611x over previous
//
#include <hip/hip_runtime.h>

#define NN 50000
#define NE 800000

typedef float fvec4 __attribute__((ext_vector_type(4)));  // clang-native for nt stores

// ---- bf16 helpers (manual RNE; values are finite) --------------------------
__device__ inline unsigned short f2bf(float f) {
    unsigned u = __float_as_uint(f);
    unsigned r = (u + 0x7FFFu + ((u >> 16) & 1u)) >> 16;
    return (unsigned short)r;
}
__device__ inline float bf2f(unsigned short h) {
    return __uint_as_float(((unsigned)h) << 16);
}

// ---- fused: degree/cursor atomics + proj0 (feat @ W0, UNscaled) ------------
// Degree role is memory-side atomic-RMW bound (~33B/atomic of HBM traffic;
// in-flight depth doesn't matter, r3/r4). proj0 rides along on the
// otherwise-idle CUs. Role by blockIdx: bid%3==0 -> degree block (391 blocks,
// 2048 edges, 8/thread), else proj tile (782). dout_is scaling lives in
// gather-0 ((s*x)@W == s*(x@W)). Streaming accesses (src/dst/epos) are
// NON-TEMPORAL: single-touch, keep them out of L2.
__global__ __launch_bounds__(256) void fused_build_proj0_kernel(
    const float* __restrict__ A,          // feat, lda=256
    const float* __restrict__ W,          // 256x64 row-major
    unsigned short* __restrict__ Xh,      // bf16 out, 50000x64
    const int* __restrict__ src, const int* __restrict__ dst,
    int* __restrict__ dout_cnt, int* __restrict__ cursor,
    int* __restrict__ epos) {
    __shared__ float sAT[64 * 68];  // [k][row], pitch 68
    __shared__ float sW[64 * 64];   // [k][col]

    const int bid = blockIdx.x;
    if (bid % 3 == 0) {
        // ---- degree / CSR-slot role: 8 edges per thread, atomics unrolled --
        const int d = bid / 3;                  // 0..390
        const int e0 = d * 2048 + threadIdx.x;  // stride-256 over 8 slots
        int s[8], dn[8], p[8];
#pragma unroll
        for (int j = 0; j < 8; ++j) {
            int e = e0 + j * 256;
            if (e < NE) {
                s[j] = __builtin_nontemporal_load(&src[e]);
                dn[j] = __builtin_nontemporal_load(&dst[e]);
            } else dn[j] = -1;
        }
#pragma unroll
        for (int j = 0; j < 8; ++j)
            if (dn[j] >= 0) p[j] = atomicAdd(&cursor[dn[j]], 1);
#pragma unroll
        for (int j = 0; j < 8; ++j)
            if (dn[j] >= 0) atomicAdd(&dout_cnt[s[j]], 1);
#pragma unroll
        for (int j = 0; j < 8; ++j) {
            int e = e0 + j * 256;
            if (e < NE) __builtin_nontemporal_store(p[j], &epos[e]);
        }
        return;
    }

    // ---- proj role: 64x64 tile of X = feat @ W0 (no scale) ----
    const int p = bid - bid / 3 - 1;          // tile id 0..781
    constexpr int lda = 256;
    constexpr int KC = 64;
    constexpr int NCHUNK = 4;                 // K = 256
    float acc[4][4] = {};

    const int t = threadIdx.x;
    const int tx = t & 15;
    const int ty = t >> 4;
    const int row0 = p * 64;

    const int srow = t & 63;
    const int f0 = t >> 6;
    int grow = row0 + srow;
    if (grow > NN - 1) grow = NN - 1;         // clamp: loads always in-bounds
    const float* arow = A + (size_t)grow * lda;

    for (int kc = 0; kc < NCHUNK; ++kc) {
#pragma unroll
        for (int it = 0; it < 4; ++it) {
            int k = (f0 + it * 4) * 4;
            float4 a4 = *reinterpret_cast<const float4*>(arow + kc * KC + k);
            sAT[(k + 0) * 68 + srow] = a4.x;
            sAT[(k + 1) * 68 + srow] = a4.y;
            sAT[(k + 2) * 68 + srow] = a4.z;
            sAT[(k + 3) * 68 + srow] = a4.w;
        }
        {
            const float4* wsrc = reinterpret_cast<const float4*>(W + (size_t)kc * KC * 64);
            float4* wdst = reinterpret_cast<float4*>(sW);
#pragma unroll
            for (int it = 0; it < 4; ++it) wdst[t + it * 256] = wsrc[t + it * 256];
        }
        __syncthreads();
#pragma unroll 8
        for (int k = 0; k < KC; ++k) {
            float4 av = *reinterpret_cast<const float4*>(&sAT[k * 68 + ty * 4]);
            float4 wv = *reinterpret_cast<const float4*>(&sW[k * 64 + tx * 4]);
            acc[0][0] = fmaf(av.x, wv.x, acc[0][0]);
            acc[0][1] = fmaf(av.x, wv.y, acc[0][1]);
            acc[0][2] = fmaf(av.x, wv.z, acc[0][2]);
            acc[0][3] = fmaf(av.x, wv.w, acc[0][3]);
            acc[1][0] = fmaf(av.y, wv.x, acc[1][0]);
            acc[1][1] = fmaf(av.y, wv.y, acc[1][1]);
            acc[1][2] = fmaf(av.y, wv.z, acc[1][2]);
            acc[1][3] = fmaf(av.y, wv.w, acc[1][3]);
            acc[2][0] = fmaf(av.z, wv.x, acc[2][0]);
            acc[2][1] = fmaf(av.z, wv.y, acc[2][1]);
            acc[2][2] = fmaf(av.z, wv.z, acc[2][2]);
            acc[2][3] = fmaf(av.z, wv.w, acc[2][3]);
            acc[3][0] = fmaf(av.w, wv.x, acc[3][0]);
            acc[3][1] = fmaf(av.w, wv.y, acc[3][1]);
            acc[3][2] = fmaf(av.w, wv.z, acc[3][2]);
            acc[3][3] = fmaf(av.w, wv.w, acc[3][3]);
        }
        __syncthreads();
    }
#pragma unroll
    for (int i = 0; i < 4; ++i) {
        int r = row0 + ty * 4 + i;
        if (r < NN) {
            ushort4 h = {f2bf(acc[i][0]), f2bf(acc[i][1]), f2bf(acc[i][2]), f2bf(acc[i][3])};
            *reinterpret_cast<ushort4*>(Xh + (size_t)r * 64 + tx * 4) = h;
        }
    }
}

// ---- scan helpers ----------------------------------------------------------
__device__ inline int wave_incl_scan(int v) {
    int lane = threadIdx.x & 63;
#pragma unroll
    for (int off = 1; off < 64; off <<= 1) {
        int t = __shfl_up(v, off, 64);
        if (lane >= off) v += t;
    }
    return v;
}

// A: per-block local exclusive scan of in-degree; block totals to partials
__global__ void scan_local_kernel(const int* __restrict__ din_cnt,
                                  int* __restrict__ row_start,
                                  int* __restrict__ partials) {
    __shared__ int wsum[4];
    int i = blockIdx.x * 256 + threadIdx.x;
    int v = (i < NN) ? din_cnt[i] : 0;
    int lane = threadIdx.x & 63, wid = threadIdx.x >> 6;
    int incl = wave_incl_scan(v);
    if (lane == 63) wsum[wid] = incl;
    __syncthreads();
    if (threadIdx.x == 0) {
        int s = 0;
        for (int w = 0; w < 4; ++w) { int t = wsum[w]; wsum[w] = s; s += t; }
        partials[blockIdx.x] = s;
    }
    __syncthreads();
    if (i < NN) row_start[i] = incl - v + wsum[wid];
}

// B: single-block exclusive scan of the 196 partials (in place)
__global__ void scan_partials_kernel(int* __restrict__ partials, int nparts,
                                     int* __restrict__ row_start) {
    __shared__ int wsum[4];
    int v = (threadIdx.x < nparts) ? partials[threadIdx.x] : 0;
    int lane = threadIdx.x & 63, wid = threadIdx.x >> 6;
    int incl = wave_incl_scan(v);
    if (lane == 63) wsum[wid] = incl;
    __syncthreads();
    if (threadIdx.x == 0) {
        int s = 0;
        for (int w = 0; w < 4; ++w) { int t = wsum[w]; wsum[w] = s; s += t; }
        row_start[NN] = NE;  // total in-degree == edge count
    }
    __syncthreads();
    if (threadIdx.x < nparts) partials[threadIdx.x] = incl - v + wsum[wid];
}

// C: add block offsets + emit rsqrt normalizers (fused, one pass over nodes)
__global__ void scan_add_norm_kernel(int* __restrict__ row_start, const int* __restrict__ partials,
                                     const int* __restrict__ dout_cnt, const int* __restrict__ din_cnt,
                                     float* __restrict__ dout_is, float* __restrict__ din_is) {
    int i = blockIdx.x * 256 + threadIdx.x;
    if (i < NN) {
        row_start[i] += partials[blockIdx.x];
        dout_is[i] = rsqrtf(fmaxf((float)dout_cnt[i], 1.0f));
        din_is[i]  = rsqrtf(fmaxf((float)din_cnt[i], 1.0f));
    }
}

// fill CSR: atomic-free scattered write using precomputed slots.
// src/dst/epos are single-touch streams -> non-temporal loads.
__global__ void csr_fill_kernel(const int* __restrict__ src, const int* __restrict__ dst,
                                const int* __restrict__ row_start, const int* __restrict__ epos,
                                int* __restrict__ csr_src) {
    int e = blockIdx.x * 256 + threadIdx.x;
    if (e < NE) {
        int d = __builtin_nontemporal_load(&dst[e]);
        int s = __builtin_nontemporal_load(&src[e]);
        int p = __builtin_nontemporal_load(&epos[e]);
        csr_src[row_start[d] + p] = s;
    }
}

// ---- X = rowscale(A) @ W, register-blocked 64x64 tile (layers 1-3, tail) ---
template <int K, bool OUT_BF16>
__global__ __launch_bounds__(256) void proj_kernel(
    const float* __restrict__ A, int lda,
    const float* __restrict__ W,   // K x 64, row-major
    const float* __restrict__ scale,
    void* __restrict__ Xout) {
    constexpr int KC = 64;
    constexpr int NCHUNK = K / KC;
    __shared__ float sAT[KC * 68];  // [k][row], pitch 68
    __shared__ float sW[KC * 64];   // [k][col]
    float acc[4][4] = {};

    const int t = threadIdx.x;
    const int tx = t & 15;          // col group: cols 4*tx..4*tx+3
    const int ty = t >> 4;          // row group: rows 4*ty..4*ty+3
    const int row0 = blockIdx.x * 64;

    const int srow = t & 63;        // staging: one row per lane
    const int f0 = t >> 6;          // staging float4-col base (0..3)
    int grow = row0 + srow;
    if (grow > NN - 1) grow = NN - 1;   // clamp: loads always in-bounds
    const float* arow = A + (size_t)grow * lda;

    for (int kc = 0; kc < NCHUNK; ++kc) {
#pragma unroll
        for (int it = 0; it < 4; ++it) {
            int k = (f0 + it * 4) * 4;
            float4 a4 = *reinterpret_cast<const float4*>(arow + kc * KC + k);
            sAT[(k + 0) * 68 + srow] = a4.x;
            sAT[(k + 1) * 68 + srow] = a4.y;
            sAT[(k + 2) * 68 + srow] = a4.z;
            sAT[(k + 3) * 68 + srow] = a4.w;
        }
        {
            const float4* wsrc = reinterpret_cast<const float4*>(W + (size_t)kc * KC * 64);
            float4* wdst = reinterpret_cast<float4*>(sW);
#pragma unroll
            for (int it = 0; it < 4; ++it) wdst[t + it * 256] = wsrc[t + it * 256];
        }
        __syncthreads();
#pragma unroll 8
        for (int k = 0; k < KC; ++k) {
            float4 av = *reinterpret_cast<const float4*>(&sAT[k * 68 + ty * 4]);
            float4 wv = *reinterpret_cast<const float4*>(&sW[k * 64 + tx * 4]);
            acc[0][0] = fmaf(av.x, wv.x, acc[0][0]);
            acc[0][1] = fmaf(av.x, wv.y, acc[0][1]);
            acc[0][2] = fmaf(av.x, wv.z, acc[0][2]);
            acc[0][3] = fmaf(av.x, wv.w, acc[0][3]);
            acc[1][0] = fmaf(av.y, wv.x, acc[1][0]);
            acc[1][1] = fmaf(av.y, wv.y, acc[1][1]);
            acc[1][2] = fmaf(av.y, wv.z, acc[1][2]);
            acc[1][3] = fmaf(av.y, wv.w, acc[1][3]);
            acc[2][0] = fmaf(av.z, wv.x, acc[2][0]);
            acc[2][1] = fmaf(av.z, wv.y, acc[2][1]);
            acc[2][2] = fmaf(av.z, wv.z, acc[2][2]);
            acc[2][3] = fmaf(av.z, wv.w, acc[2][3]);
            acc[3][0] = fmaf(av.w, wv.x, acc[3][0]);
            acc[3][1] = fmaf(av.w, wv.y, acc[3][1]);
            acc[3][2] = fmaf(av.w, wv.z, acc[3][2]);
            acc[3][3] = fmaf(av.w, wv.w, acc[3][3]);
        }
        __syncthreads();
    }
#pragma unroll
    for (int i = 0; i < 4; ++i) {
        int r = row0 + ty * 4 + i;
        if (r < NN) {
            float s = scale ? scale[r] : 1.0f;
            float4 o = {acc[i][0] * s, acc[i][1] * s, acc[i][2] * s, acc[i][3] * s};
            if (OUT_BF16) {
                ushort4 h = {f2bf(o.x), f2bf(o.y), f2bf(o.z), f2bf(o.w)};
                *reinterpret_cast<ushort4*>((unsigned short*)Xout + (size_t)r * 64 + tx * 4) = h;
            } else {
                *reinterpret_cast<float4*>((float*)Xout + (size_t)r * 64 + tx * 4) = o;
            }
        }
    }
}

// ---- pull aggregation: 8 groups x 8 cols, uint4 loads, f32 accumulate ------
// One wave per dst row. lane = group g (lane>>3) x col-oct ((lane&7)*8).
// uint4 (16B) row loads; bf16 unpack via shift/and; f32 accumulate.
// NON-TEMPORAL on the single-touch streams (csr_src loads, output stores):
// keeps L2 capacity for the X table (~16 reads/row, the only reused data).
// This attacks the eviction mechanism that defeated r5-r7's residency
// attempts. X loads and sscale loads stay cacheable.
template <bool SSCALE>
__device__ inline void acc8(float* a, uint4 v, float w) {
    unsigned d0 = v.x, d1 = v.y, d2 = v.z, d3 = v.w;
    if (SSCALE) {
        a[0] = fmaf(__uint_as_float(d0 << 16), w, a[0]);
        a[1] = fmaf(__uint_as_float(d0 & 0xFFFF0000u), w, a[1]);
        a[2] = fmaf(__uint_as_float(d1 << 16), w, a[2]);
        a[3] = fmaf(__uint_as_float(d1 & 0xFFFF0000u), w, a[3]);
        a[4] = fmaf(__uint_as_float(d2 << 16), w, a[4]);
        a[5] = fmaf(__uint_as_float(d2 & 0xFFFF0000u), w, a[5]);
        a[6] = fmaf(__uint_as_float(d3 << 16), w, a[6]);
        a[7] = fmaf(__uint_as_float(d3 & 0xFFFF0000u), w, a[7]);
    } else {
        a[0] += __uint_as_float(d0 << 16);
        a[1] += __uint_as_float(d0 & 0xFFFF0000u);
        a[2] += __uint_as_float(d1 << 16);
        a[3] += __uint_as_float(d1 & 0xFFFF0000u);
        a[4] += __uint_as_float(d2 << 16);
        a[5] += __uint_as_float(d2 & 0xFFFF0000u);
        a[6] += __uint_as_float(d3 << 16);
        a[7] += __uint_as_float(d3 & 0xFFFF0000u);
    }
}

template <bool SSCALE>
__global__ __launch_bounds__(256) void gather8_bf16_kernel(
    const int* __restrict__ row_start, const int* __restrict__ csr_src,
    const unsigned short* __restrict__ Xh, const float* __restrict__ din_is,
    const float* __restrict__ sscale,
    const float* __restrict__ b, float* __restrict__ out,
    int ldo, int coff, int relu) {
    int n = blockIdx.x * 4 + (threadIdx.x >> 6);
    if (n >= NN) return;
    int lane = threadIdx.x & 63;
    int g = lane >> 3;              // neighbor group 0..7
    int c8 = (lane & 7) << 3;       // cols c8..c8+7
    int s0 = row_start[n], s1 = row_start[n + 1];
    float a[8] = {};
    int i = s0;
    // 16 neighbors/iter: 2 independent 16B row loads in flight per lane
    for (; i + 16 <= s1; i += 16) {
        int ia = __builtin_nontemporal_load(&csr_src[i + g]);
        int ib = __builtin_nontemporal_load(&csr_src[i + 8 + g]);
        uint4 va = *reinterpret_cast<const uint4*>(Xh + (size_t)ia * 64 + c8);
        uint4 vb = *reinterpret_cast<const uint4*>(Xh + (size_t)ib * 64 + c8);
        float wa = SSCALE ? sscale[ia] : 1.0f;
        float wb = SSCALE ? sscale[ib] : 1.0f;
        acc8<SSCALE>(a, va, wa);
        acc8<SSCALE>(a, vb, wb);
    }
    // 8 neighbors/iter
    for (; i + 8 <= s1; i += 8) {
        int ia = __builtin_nontemporal_load(&csr_src[i + g]);
        uint4 va = *reinterpret_cast<const uint4*>(Xh + (size_t)ia * 64 + c8);
        float wa = SSCALE ? sscale[ia] : 1.0f;
        acc8<SSCALE>(a, va, wa);
    }
    // <8 remaining, group-guarded
    if (i + g < s1) {
        int ia = __builtin_nontemporal_load(&csr_src[i + g]);
        uint4 va = *reinterpret_cast<const uint4*>(Xh + (size_t)ia * 64 + c8);
        float wa = SSCALE ? sscale[ia] : 1.0f;
        acc8<SSCALE>(a, va, wa);
    }
    // combine the 8 groups (lanes l, l^8, l^16, ..., l^56 share the same c8)
#pragma unroll
    for (int off = 8; off < 64; off <<= 1) {
#pragma unroll
        for (int j = 0; j < 8; ++j) a[j] += __shfl_xor(a[j], off, 64);
    }
    if (g == 0) {
        fvec4 o0, o1;
        if (relu) {
            float di = din_is[n];
            o0.x = fmaxf(fmaf(a[0], di, b[c8 + 0]), 0.0f);
            o0.y = fmaxf(fmaf(a[1], di, b[c8 + 1]), 0.0f);
            o0.z = fmaxf(fmaf(a[2], di, b[c8 + 2]), 0.0f);
            o0.w = fmaxf(fmaf(a[3], di, b[c8 + 3]), 0.0f);
            o1.x = fmaxf(fmaf(a[4], di, b[c8 + 4]), 0.0f);
            o1.y = fmaxf(fmaf(a[5], di, b[c8 + 5]), 0.0f);
            o1.z = fmaxf(fmaf(a[6], di, b[c8 + 6]), 0.0f);
            o1.w = fmaxf(fmaf(a[7], di, b[c8 + 7]), 0.0f);
        } else {
            o0.x = a[0] + b[c8 + 0];
            o0.y = a[1] + b[c8 + 1];
            o0.z = a[2] + b[c8 + 2];
            o0.w = a[3] + b[c8 + 3];
            o1.x = a[4] + b[c8 + 4];
            o1.y = a[5] + b[c8 + 5];
            o1.z = a[6] + b[c8 + 6];
            o1.w = a[7] + b[c8 + 7];
        }
        float* op = out + (size_t)n * ldo + coff + c8;
        __builtin_nontemporal_store(o0, reinterpret_cast<fvec4*>(op));
        __builtin_nontemporal_store(o1, reinterpret_cast<fvec4*>(op + 4));
    }
}

extern "C" void kernel_launch(void* const* d_in, const int* in_sizes, int n_in,
                              void* d_out, int out_size, void* d_ws, size_t ws_size,
                              hipStream_t stream) {
    const float* feat  = (const float*)d_in[0];
    const int*   src   = (const int*)d_in[1];
    const int*   dst   = (const int*)d_in[2];
    const float* W[4]  = {(const float*)d_in[3], (const float*)d_in[5],
                          (const float*)d_in[7], (const float*)d_in[9]};
    const float* b[4]  = {(const float*)d_in[4], (const float*)d_in[6],
                          (const float*)d_in[8], (const float*)d_in[10]};
    const float* W_mlp = (const float*)d_in[11];
    const float* b_mlp = (const float*)d_in[12];
    float* out = (float*)d_out;

    // workspace layout:
    // C [NN*256 f]  (head transiently reused: dout_cnt [NN i] | cursor [NN i]
    //               | epos [NE i] — all dead before gather-0 writes C)
    // X [NN*64 f]   (bf16 view aliases the same region)
    // dout_is [NN f] | din_is [NN f] |
    // row_start [NN+1 i] | partials [256 i] | csr_src [NE i]
    float* C        = (float*)d_ws;
    int*   dout_cnt = (int*)d_ws;            // NN
    int*   cursor   = dout_cnt + NN;         // NN (doubles as din_cnt)
    int*   epos     = cursor + NN;           // NE
    float* X        = C + (size_t)NN * 256;
    unsigned short* Xh = (unsigned short*)X; // bf16 alias (used disjointly in time)
    float* dout_is  = X + (size_t)NN * 64;
    float* din_is   = dout_is + NN;
    int*   row_start = (int*)(din_is + NN);
    int*   partials  = row_start + NN + 1;
    int*   csr_src   = partials + 256;

    const int NBLK = (NN + 255) / 256;   // 196
    const int GBLK = (NN + 63) / 64;     // 782 (GEMM tiles)
    const int EBLK = (NE + 255) / 256;   // 3125
    const int DEGBLK = (NE + 2047) / 2048;  // 391 degree blocks (8 edges/thread)
    const int FBLK = GBLK + DEGBLK;      // 1173 fused blocks (391 degree @ bid%3==0)

    // zero dout_cnt + cursor (contiguous)
    hipMemsetAsync(dout_cnt, 0, 2 * NN * sizeof(int), stream);

    // fused: degree/cursor atomic pass overlapped with proj0 (unscaled feat@W0)
    fused_build_proj0_kernel<<<FBLK, 256, 0, stream>>>(feat, W[0], Xh,
                                                       src, dst, dout_cnt, cursor, epos);

    // row_start = exscan(cursor); fill is atomic-free
    scan_local_kernel<<<NBLK, 256, 0, stream>>>(cursor, row_start, partials);
    scan_partials_kernel<<<1, 256, 0, stream>>>(partials, NBLK, row_start);
    scan_add_norm_kernel<<<NBLK, 256, 0, stream>>>(row_start, partials, dout_cnt, cursor,
                                                   dout_is, din_is);
    csr_fill_kernel<<<EBLK, 256, 0, stream>>>(src, dst, row_start, epos, csr_src);

    // layer 0: X holds UNscaled feat@W0; dout_is applied per-src-row in gather
    gather8_bf16_kernel<true><<<12500, 256, 0, stream>>>(row_start, csr_src, Xh, din_is,
                                                         dout_is, b[0], C, 256, 0, 1);

    // layers 1..3 (K = 64), input = previous slice of C — bf16 X, pre-scaled
    for (int i = 1; i < 4; ++i) {
        proj_kernel<64, true><<<GBLK, 256, 0, stream>>>(C + (i - 1) * 64, 256, W[i], dout_is, Xh);
        gather8_bf16_kernel<false><<<12500, 256, 0, stream>>>(row_start, csr_src, Xh, din_is,
                                                              nullptr, b[i], C, 256, i * 64, 1);
    }

    // tail: P = C @ W_mlp as bf16 (project BEFORE the neighbor-sum; linear),
    // then out = b_mlp + segment_sum(P[src] -> dst)
    proj_kernel<256, true><<<GBLK, 256, 0, stream>>>(C, 256, W_mlp, nullptr, Xh);
    gather8_bf16_kernel<false><<<12500, 256, 0, stream>>>(row_start, csr_src, Xh, nullptr,
                                                          nullptr, b_mlp, out, 64, 0, 0);
}

// Round 10
// 388.476 us; speedup vs baseline: 1.3250x; 1.0552x over previous
//
#include <hip/hip_runtime.h>

#define NN 50000
#define NE 800000

// ---- bf16 helpers (manual RNE; values are finite) --------------------------
__device__ inline unsigned short f2bf(float f) {
    unsigned u = __float_as_uint(f);
    unsigned r = (u + 0x7FFFu + ((u >> 16) & 1u)) >> 16;
    return (unsigned short)r;
}
__device__ inline float bf2f(unsigned short h) {
    return __uint_as_float(((unsigned)h) << 16);
}

// Physical XCD id of the CU this block runs on (0..7). HW-verified on MI355X
// (learn_hip m09). Blocks never migrate, so this is block-uniform.
__device__ inline int get_xcd() {
    int x;
    asm volatile("s_getreg_b32 %0, hwreg(HW_REG_XCC_ID)" : "=s"(x));
    return x & 7;
}

// ---- fused: degree/cursor atomics + proj0 (feat @ W0, UNscaled) ------------
// KEY CHANGE (r10): device-scope atomicAdd executes at the MEMORY SIDE on
// multi-XCD CDNA (per-XCD L2s non-coherent) -> 1.6M atomics x ~33B = 52.9MB
// of the fused kernel's 59.2MB WRITE_SIZE at ~650GB/s = the ~80us floor seen
// r0-r9. Fix: per-XCD counter copies (cnt8[xcd][node], dout8[xcd][node]) +
// WORKGROUP-scope atomics -> RMW executes in the local XCD L2 (no sc1, line
// stays dirty-local; correct because only blocks on XCD x touch copy x).
// epos packs (xcd<<24)|local_slot; the scan later builds disjoint global
// slots via per-XCD prefix offsets. Cross-kernel visibility = standard HIP
// dispatch-boundary cache flush.
// Role by blockIdx: bid%3==0 -> degree block (391 blocks, 2048 edges,
// 8/thread), else proj tile (782). dout_is scaling lives in gather-0.
__global__ __launch_bounds__(256) void fused_build_proj0_kernel(
    const float* __restrict__ A,          // feat, lda=256
    const float* __restrict__ W,          // 256x64 row-major
    unsigned short* __restrict__ Xh,      // bf16 out, 50000x64
    const int* __restrict__ src, const int* __restrict__ dst,
    int* __restrict__ cnt8,               // 8 x NN per-XCD in-degree counters
    int* __restrict__ dout8,              // 8 x NN per-XCD out-degree counters
    int* __restrict__ epos) {
    __shared__ float sAT[64 * 68];  // [k][row], pitch 68
    __shared__ float sW[64 * 64];   // [k][col]

    const int bid = blockIdx.x;
    if (bid % 3 == 0) {
        // ---- degree / CSR-slot role: 8 edges per thread, L2-local atomics --
        const int xcd = get_xcd();
        int* mycnt  = cnt8  + (size_t)xcd * NN;
        int* mydout = dout8 + (size_t)xcd * NN;
        const int d = bid / 3;                  // 0..390
        const int e0 = d * 2048 + threadIdx.x;  // stride-256 over 8 slots
        int s[8], dn[8], p[8];
#pragma unroll
        for (int j = 0; j < 8; ++j) {
            int e = e0 + j * 256;
            if (e < NE) { s[j] = src[e]; dn[j] = dst[e]; } else dn[j] = -1;
        }
#pragma unroll
        for (int j = 0; j < 8; ++j)
            if (dn[j] >= 0)
                p[j] = __hip_atomic_fetch_add(&mycnt[dn[j]], 1,
                                              __ATOMIC_RELAXED,
                                              __HIP_MEMORY_SCOPE_WORKGROUP);
#pragma unroll
        for (int j = 0; j < 8; ++j)
            if (dn[j] >= 0)
                __hip_atomic_fetch_add(&mydout[s[j]], 1,
                                       __ATOMIC_RELAXED,
                                       __HIP_MEMORY_SCOPE_WORKGROUP);
#pragma unroll
        for (int j = 0; j < 8; ++j) {
            int e = e0 + j * 256;
            if (e < NE) epos[e] = (xcd << 24) | p[j];
        }
        return;
    }

    // ---- proj role: 64x64 tile of X = feat @ W0 (no scale) ----
    const int p = bid - bid / 3 - 1;          // tile id 0..781
    constexpr int lda = 256;
    constexpr int KC = 64;
    constexpr int NCHUNK = 4;                 // K = 256
    float acc[4][4] = {};

    const int t = threadIdx.x;
    const int tx = t & 15;
    const int ty = t >> 4;
    const int row0 = p * 64;

    const int srow = t & 63;
    const int f0 = t >> 6;
    int grow = row0 + srow;
    if (grow > NN - 1) grow = NN - 1;         // clamp: loads always in-bounds
    const float* arow = A + (size_t)grow * lda;

    for (int kc = 0; kc < NCHUNK; ++kc) {
#pragma unroll
        for (int it = 0; it < 4; ++it) {
            int k = (f0 + it * 4) * 4;
            float4 a4 = *reinterpret_cast<const float4*>(arow + kc * KC + k);
            sAT[(k + 0) * 68 + srow] = a4.x;
            sAT[(k + 1) * 68 + srow] = a4.y;
            sAT[(k + 2) * 68 + srow] = a4.z;
            sAT[(k + 3) * 68 + srow] = a4.w;
        }
        {
            const float4* wsrc = reinterpret_cast<const float4*>(W + (size_t)kc * KC * 64);
            float4* wdst = reinterpret_cast<float4*>(sW);
#pragma unroll
            for (int it = 0; it < 4; ++it) wdst[t + it * 256] = wsrc[t + it * 256];
        }
        __syncthreads();
#pragma unroll 8
        for (int k = 0; k < KC; ++k) {
            float4 av = *reinterpret_cast<const float4*>(&sAT[k * 68 + ty * 4]);
            float4 wv = *reinterpret_cast<const float4*>(&sW[k * 64 + tx * 4]);
            acc[0][0] = fmaf(av.x, wv.x, acc[0][0]);
            acc[0][1] = fmaf(av.x, wv.y, acc[0][1]);
            acc[0][2] = fmaf(av.x, wv.z, acc[0][2]);
            acc[0][3] = fmaf(av.x, wv.w, acc[0][3]);
            acc[1][0] = fmaf(av.y, wv.x, acc[1][0]);
            acc[1][1] = fmaf(av.y, wv.y, acc[1][1]);
            acc[1][2] = fmaf(av.y, wv.z, acc[1][2]);
            acc[1][3] = fmaf(av.y, wv.w, acc[1][3]);
            acc[2][0] = fmaf(av.z, wv.x, acc[2][0]);
            acc[2][1] = fmaf(av.z, wv.y, acc[2][1]);
            acc[2][2] = fmaf(av.z, wv.z, acc[2][2]);
            acc[2][3] = fmaf(av.z, wv.w, acc[2][3]);
            acc[3][0] = fmaf(av.w, wv.x, acc[3][0]);
            acc[3][1] = fmaf(av.w, wv.y, acc[3][1]);
            acc[3][2] = fmaf(av.w, wv.z, acc[3][2]);
            acc[3][3] = fmaf(av.w, wv.w, acc[3][3]);
        }
        __syncthreads();
    }
#pragma unroll
    for (int i = 0; i < 4; ++i) {
        int r = row0 + ty * 4 + i;
        if (r < NN) {
            ushort4 h = {f2bf(acc[i][0]), f2bf(acc[i][1]), f2bf(acc[i][2]), f2bf(acc[i][3])};
            *reinterpret_cast<ushort4*>(Xh + (size_t)r * 64 + tx * 4) = h;
        }
    }
}

// ---- scan helpers ----------------------------------------------------------
__device__ inline int wave_incl_scan(int v) {
    int lane = threadIdx.x & 63;
#pragma unroll
    for (int off = 1; off < 64; off <<= 1) {
        int t = __shfl_up(v, off, 64);
        if (lane >= off) v += t;
    }
    return v;
}

// A: per-block local exclusive scan of in-degree (sum of 8 XCD copies)
__global__ void scan_local_kernel(const int* __restrict__ cnt8,
                                  int* __restrict__ row_start,
                                  int* __restrict__ partials) {
    __shared__ int wsum[4];
    int i = blockIdx.x * 256 + threadIdx.x;
    int v = 0;
    if (i < NN) {
#pragma unroll
        for (int x = 0; x < 8; ++x) v += cnt8[(size_t)x * NN + i];
    }
    int lane = threadIdx.x & 63, wid = threadIdx.x >> 6;
    int incl = wave_incl_scan(v);
    if (lane == 63) wsum[wid] = incl;
    __syncthreads();
    if (threadIdx.x == 0) {
        int s = 0;
        for (int w = 0; w < 4; ++w) { int t = wsum[w]; wsum[w] = s; s += t; }
        partials[blockIdx.x] = s;
    }
    __syncthreads();
    if (i < NN) row_start[i] = incl - v + wsum[wid];
}

// B: single-block exclusive scan of the 196 partials (in place)
__global__ void scan_partials_kernel(int* __restrict__ partials, int nparts,
                                     int* __restrict__ row_start) {
    __shared__ int wsum[4];
    int v = (threadIdx.x < nparts) ? partials[threadIdx.x] : 0;
    int lane = threadIdx.x & 63, wid = threadIdx.x >> 6;
    int incl = wave_incl_scan(v);
    if (lane == 63) wsum[wid] = incl;
    __syncthreads();
    if (threadIdx.x == 0) {
        int s = 0;
        for (int w = 0; w < 4; ++w) { int t = wsum[w]; wsum[w] = s; s += t; }
        row_start[NN] = NE;  // total in-degree == edge count
    }
    __syncthreads();
    if (threadIdx.x < nparts) partials[threadIdx.x] = incl - v + wsum[wid];
}

// C: add block offsets + per-XCD slot bases + rsqrt normalizers (one pass)
// base8[x][i] = row_start[i] + sum_{x'<x} cnt8[x'][i]  (disjoint global slots)
__global__ void scan_add_norm_kernel(int* __restrict__ row_start, const int* __restrict__ partials,
                                     const int* __restrict__ cnt8, const int* __restrict__ dout8,
                                     int* __restrict__ base8,
                                     float* __restrict__ dout_is, float* __restrict__ din_is) {
    int i = blockIdx.x * 256 + threadIdx.x;
    if (i < NN) {
        int rs = row_start[i] + partials[blockIdx.x];
        row_start[i] = rs;
        int run = 0;
#pragma unroll
        for (int x = 0; x < 8; ++x) {
            base8[(size_t)x * NN + i] = rs + run;
            run += cnt8[(size_t)x * NN + i];
        }
        int dout = 0;
#pragma unroll
        for (int x = 0; x < 8; ++x) dout += dout8[(size_t)x * NN + i];
        din_is[i]  = rsqrtf(fmaxf((float)run, 1.0f));
        dout_is[i] = rsqrtf(fmaxf((float)dout, 1.0f));
    }
}

// fill CSR: atomic-free scattered write; decode (xcd, local slot) from epos
__global__ void csr_fill_kernel(const int* __restrict__ src, const int* __restrict__ dst,
                                const int* __restrict__ base8, const int* __restrict__ epos,
                                int* __restrict__ csr_src) {
    int e = blockIdx.x * 256 + threadIdx.x;
    if (e < NE) {
        int pe = epos[e];
        int xcd = pe >> 24, lslot = pe & 0xFFFFFF;
        csr_src[base8[(size_t)xcd * NN + dst[e]] + lslot] = src[e];
    }
}

// ---- X = rowscale(A) @ W, register-blocked 64x64 tile (layers 1-3, tail) ---
template <int K, bool OUT_BF16>
__global__ __launch_bounds__(256) void proj_kernel(
    const float* __restrict__ A, int lda,
    const float* __restrict__ W,   // K x 64, row-major
    const float* __restrict__ scale,
    void* __restrict__ Xout) {
    constexpr int KC = 64;
    constexpr int NCHUNK = K / KC;
    __shared__ float sAT[KC * 68];  // [k][row], pitch 68
    __shared__ float sW[KC * 64];   // [k][col]
    float acc[4][4] = {};

    const int t = threadIdx.x;
    const int tx = t & 15;          // col group: cols 4*tx..4*tx+3
    const int ty = t >> 4;          // row group: rows 4*ty..4*ty+3
    const int row0 = blockIdx.x * 64;

    const int srow = t & 63;        // staging: one row per lane
    const int f0 = t >> 6;          // staging float4-col base (0..3)
    int grow = row0 + srow;
    if (grow > NN - 1) grow = NN - 1;   // clamp: loads always in-bounds
    const float* arow = A + (size_t)grow * lda;

    for (int kc = 0; kc < NCHUNK; ++kc) {
#pragma unroll
        for (int it = 0; it < 4; ++it) {
            int k = (f0 + it * 4) * 4;
            float4 a4 = *reinterpret_cast<const float4*>(arow + kc * KC + k);
            sAT[(k + 0) * 68 + srow] = a4.x;
            sAT[(k + 1) * 68 + srow] = a4.y;
            sAT[(k + 2) * 68 + srow] = a4.z;
            sAT[(k + 3) * 68 + srow] = a4.w;
        }
        {
            const float4* wsrc = reinterpret_cast<const float4*>(W + (size_t)kc * KC * 64);
            float4* wdst = reinterpret_cast<float4*>(sW);
#pragma unroll
            for (int it = 0; it < 4; ++it) wdst[t + it * 256] = wsrc[t + it * 256];
        }
        __syncthreads();
#pragma unroll 8
        for (int k = 0; k < KC; ++k) {
            float4 av = *reinterpret_cast<const float4*>(&sAT[k * 68 + ty * 4]);
            float4 wv = *reinterpret_cast<const float4*>(&sW[k * 64 + tx * 4]);
            acc[0][0] = fmaf(av.x, wv.x, acc[0][0]);
            acc[0][1] = fmaf(av.x, wv.y, acc[0][1]);
            acc[0][2] = fmaf(av.x, wv.z, acc[0][2]);
            acc[0][3] = fmaf(av.x, wv.w, acc[0][3]);
            acc[1][0] = fmaf(av.y, wv.x, acc[1][0]);
            acc[1][1] = fmaf(av.y, wv.y, acc[1][1]);
            acc[1][2] = fmaf(av.y, wv.z, acc[1][2]);
            acc[1][3] = fmaf(av.y, wv.w, acc[1][3]);
            acc[2][0] = fmaf(av.z, wv.x, acc[2][0]);
            acc[2][1] = fmaf(av.z, wv.y, acc[2][1]);
            acc[2][2] = fmaf(av.z, wv.z, acc[2][2]);
            acc[2][3] = fmaf(av.z, wv.w, acc[2][3]);
            acc[3][0] = fmaf(av.w, wv.x, acc[3][0]);
            acc[3][1] = fmaf(av.w, wv.y, acc[3][1]);
            acc[3][2] = fmaf(av.w, wv.z, acc[3][2]);
            acc[3][3] = fmaf(av.w, wv.w, acc[3][3]);
        }
        __syncthreads();
    }
#pragma unroll
    for (int i = 0; i < 4; ++i) {
        int r = row0 + ty * 4 + i;
        if (r < NN) {
            float s = scale ? scale[r] : 1.0f;
            float4 o = {acc[i][0] * s, acc[i][1] * s, acc[i][2] * s, acc[i][3] * s};
            if (OUT_BF16) {
                ushort4 h = {f2bf(o.x), f2bf(o.y), f2bf(o.z), f2bf(o.w)};
                *reinterpret_cast<ushort4*>((unsigned short*)Xout + (size_t)r * 64 + tx * 4) = h;
            } else {
                *reinterpret_cast<float4*>((float*)Xout + (size_t)r * 64 + tx * 4) = o;
            }
        }
    }
}

// ---- pull aggregation: 8 groups x 8 cols, uint4 loads, f32 accumulate ------
// (r4 version, best measured; all nt hints reverted — r9 showed nt −28us.)
template <bool SSCALE>
__device__ inline void acc8(float* a, uint4 v, float w) {
    unsigned d0 = v.x, d1 = v.y, d2 = v.z, d3 = v.w;
    if (SSCALE) {
        a[0] = fmaf(__uint_as_float(d0 << 16), w, a[0]);
        a[1] = fmaf(__uint_as_float(d0 & 0xFFFF0000u), w, a[1]);
        a[2] = fmaf(__uint_as_float(d1 << 16), w, a[2]);
        a[3] = fmaf(__uint_as_float(d1 & 0xFFFF0000u), w, a[3]);
        a[4] = fmaf(__uint_as_float(d2 << 16), w, a[4]);
        a[5] = fmaf(__uint_as_float(d2 & 0xFFFF0000u), w, a[5]);
        a[6] = fmaf(__uint_as_float(d3 << 16), w, a[6]);
        a[7] = fmaf(__uint_as_float(d3 & 0xFFFF0000u), w, a[7]);
    } else {
        a[0] += __uint_as_float(d0 << 16);
        a[1] += __uint_as_float(d0 & 0xFFFF0000u);
        a[2] += __uint_as_float(d1 << 16);
        a[3] += __uint_as_float(d1 & 0xFFFF0000u);
        a[4] += __uint_as_float(d2 << 16);
        a[5] += __uint_as_float(d2 & 0xFFFF0000u);
        a[6] += __uint_as_float(d3 << 16);
        a[7] += __uint_as_float(d3 & 0xFFFF0000u);
    }
}

template <bool SSCALE>
__global__ __launch_bounds__(256) void gather8_bf16_kernel(
    const int* __restrict__ row_start, const int* __restrict__ csr_src,
    const unsigned short* __restrict__ Xh, const float* __restrict__ din_is,
    const float* __restrict__ sscale,
    const float* __restrict__ b, float* __restrict__ out,
    int ldo, int coff, int relu) {
    int n = blockIdx.x * 4 + (threadIdx.x >> 6);
    if (n >= NN) return;
    int lane = threadIdx.x & 63;
    int g = lane >> 3;              // neighbor group 0..7
    int c8 = (lane & 7) << 3;       // cols c8..c8+7
    int s0 = row_start[n], s1 = row_start[n + 1];
    float a[8] = {};
    int i = s0;
    // 16 neighbors/iter: 2 independent 16B row loads in flight per lane
    for (; i + 16 <= s1; i += 16) {
        int ia = csr_src[i + g];
        int ib = csr_src[i + 8 + g];
        uint4 va = *reinterpret_cast<const uint4*>(Xh + (size_t)ia * 64 + c8);
        uint4 vb = *reinterpret_cast<const uint4*>(Xh + (size_t)ib * 64 + c8);
        float wa = SSCALE ? sscale[ia] : 1.0f;
        float wb = SSCALE ? sscale[ib] : 1.0f;
        acc8<SSCALE>(a, va, wa);
        acc8<SSCALE>(a, vb, wb);
    }
    // 8 neighbors/iter
    for (; i + 8 <= s1; i += 8) {
        int ia = csr_src[i + g];
        uint4 va = *reinterpret_cast<const uint4*>(Xh + (size_t)ia * 64 + c8);
        float wa = SSCALE ? sscale[ia] : 1.0f;
        acc8<SSCALE>(a, va, wa);
    }
    // <8 remaining, group-guarded
    if (i + g < s1) {
        int ia = csr_src[i + g];
        uint4 va = *reinterpret_cast<const uint4*>(Xh + (size_t)ia * 64 + c8);
        float wa = SSCALE ? sscale[ia] : 1.0f;
        acc8<SSCALE>(a, va, wa);
    }
    // combine the 8 groups (lanes l, l^8, l^16, ..., l^56 share the same c8)
#pragma unroll
    for (int off = 8; off < 64; off <<= 1) {
#pragma unroll
        for (int j = 0; j < 8; ++j) a[j] += __shfl_xor(a[j], off, 64);
    }
    if (g == 0) {
        float4 o0, o1;
        if (relu) {
            float di = din_is[n];
            o0.x = fmaxf(fmaf(a[0], di, b[c8 + 0]), 0.0f);
            o0.y = fmaxf(fmaf(a[1], di, b[c8 + 1]), 0.0f);
            o0.z = fmaxf(fmaf(a[2], di, b[c8 + 2]), 0.0f);
            o0.w = fmaxf(fmaf(a[3], di, b[c8 + 3]), 0.0f);
            o1.x = fmaxf(fmaf(a[4], di, b[c8 + 4]), 0.0f);
            o1.y = fmaxf(fmaf(a[5], di, b[c8 + 5]), 0.0f);
            o1.z = fmaxf(fmaf(a[6], di, b[c8 + 6]), 0.0f);
            o1.w = fmaxf(fmaf(a[7], di, b[c8 + 7]), 0.0f);
        } else {
            o0.x = a[0] + b[c8 + 0];
            o0.y = a[1] + b[c8 + 1];
            o0.z = a[2] + b[c8 + 2];
            o0.w = a[3] + b[c8 + 3];
            o1.x = a[4] + b[c8 + 4];
            o1.y = a[5] + b[c8 + 5];
            o1.z = a[6] + b[c8 + 6];
            o1.w = a[7] + b[c8 + 7];
        }
        float* op = out + (size_t)n * ldo + coff + c8;
        *reinterpret_cast<float4*>(op) = o0;
        *reinterpret_cast<float4*>(op + 4) = o1;
    }
}

extern "C" void kernel_launch(void* const* d_in, const int* in_sizes, int n_in,
                              void* d_out, int out_size, void* d_ws, size_t ws_size,
                              hipStream_t stream) {
    const float* feat  = (const float*)d_in[0];
    const int*   src   = (const int*)d_in[1];
    const int*   dst   = (const int*)d_in[2];
    const float* W[4]  = {(const float*)d_in[3], (const float*)d_in[5],
                          (const float*)d_in[7], (const float*)d_in[9]};
    const float* b[4]  = {(const float*)d_in[4], (const float*)d_in[6],
                          (const float*)d_in[8], (const float*)d_in[10]};
    const float* W_mlp = (const float*)d_in[11];
    const float* b_mlp = (const float*)d_in[12];
    float* out = (float*)d_out;

    // workspace layout:
    // C [NN*256 f]  (head transiently reused: cnt8 [8NN i] | dout8 [8NN i]
    //               | base8 [8NN i] | epos [NE i] — all dead before gather-0
    //               writes C)
    // X [NN*64 f]   (bf16 view aliases the same region)
    // dout_is [NN f] | din_is [NN f] |
    // row_start [NN+1 i] | partials [256 i] | csr_src [NE i]
    float* C        = (float*)d_ws;
    int*   cnt8     = (int*)d_ws;            // 8*NN
    int*   dout8    = cnt8 + 8 * NN;         // 8*NN
    int*   base8    = dout8 + 8 * NN;        // 8*NN
    int*   epos     = base8 + 8 * NN;        // NE
    float* X        = C + (size_t)NN * 256;
    unsigned short* Xh = (unsigned short*)X; // bf16 alias (used disjointly in time)
    float* dout_is  = X + (size_t)NN * 64;
    float* din_is   = dout_is + NN;
    int*   row_start = (int*)(din_is + NN);
    int*   partials  = row_start + NN + 1;
    int*   csr_src   = partials + 256;

    const int NBLK = (NN + 255) / 256;   // 196
    const int GBLK = (NN + 63) / 64;     // 782 (GEMM tiles)
    const int EBLK = (NE + 255) / 256;   // 3125
    const int DEGBLK = (NE + 2047) / 2048;  // 391 degree blocks (8 edges/thread)
    const int FBLK = GBLK + DEGBLK;      // 1173 fused blocks (391 degree @ bid%3==0)

    // zero cnt8 + dout8 (contiguous, 16*NN ints = 3.2MB)
    hipMemsetAsync(cnt8, 0, 16 * NN * sizeof(int), stream);

    // fused: degree pass (per-XCD L2-local atomics) overlapped with proj0
    fused_build_proj0_kernel<<<FBLK, 256, 0, stream>>>(feat, W[0], Xh,
                                                       src, dst, cnt8, dout8, epos);

    // row_start = exscan(sum cnt8); per-XCD slot bases; fill is atomic-free
    scan_local_kernel<<<NBLK, 256, 0, stream>>>(cnt8, row_start, partials);
    scan_partials_kernel<<<1, 256, 0, stream>>>(partials, NBLK, row_start);
    scan_add_norm_kernel<<<NBLK, 256, 0, stream>>>(row_start, partials, cnt8, dout8,
                                                   base8, dout_is, din_is);
    csr_fill_kernel<<<EBLK, 256, 0, stream>>>(src, dst, base8, epos, csr_src);

    // layer 0: X holds UNscaled feat@W0; dout_is applied per-src-row in gather
    gather8_bf16_kernel<true><<<12500, 256, 0, stream>>>(row_start, csr_src, Xh, din_is,
                                                         dout_is, b[0], C, 256, 0, 1);

    // layers 1..3 (K = 64), input = previous slice of C — bf16 X, pre-scaled
    for (int i = 1; i < 4; ++i) {
        proj_kernel<64, true><<<GBLK, 256, 0, stream>>>(C + (i - 1) * 64, 256, W[i], dout_is, Xh);
        gather8_bf16_kernel<false><<<12500, 256, 0, stream>>>(row_start, csr_src, Xh, din_is,
                                                              nullptr, b[i], C, 256, i * 64, 1);
    }

    // tail: P = C @ W_mlp as bf16 (project BEFORE the neighbor-sum; linear),
    // then out = b_mlp + segment_sum(P[src] -> dst)
    proj_kernel<256, true><<<GBLK, 256, 0, stream>>>(C, 256, W_mlp, nullptr, Xh);
    gather8_bf16_kernel<false><<<12500, 256, 0, stream>>>(row_start, csr_src, Xh, nullptr,
                                                          nullptr, b_mlp, out, 64, 0, 0);
}